// Round 1
// baseline (1365.719 us; speedup 1.0000x reference)
//
#include <hip/hip_runtime.h>
#include <hip/hip_bf16.h>

#define T_DIM 4096
#define H_DIM 2048
#define I_DIM 2048
#define E_NUM 16

#define BM 128
#define BN 128
#define BK 32

// padded-rows cap: sum(cnt)=8192, each expert pads +<=127 -> <=10224; use 10240
#define MAX_ROWS 10240

using frag_ab = __attribute__((ext_vector_type(8))) short;   // 8 bf16 in 4 VGPRs
using frag_cd = __attribute__((ext_vector_type(4))) float;   // 4 fp32 acc

__device__ __forceinline__ unsigned short f2bf(float f) {
    unsigned int u = __float_as_uint(f);
    u += 0x7fff + ((u >> 16) & 1);      // RNE
    return (unsigned short)(u >> 16);
}
__device__ __forceinline__ float bf2f(unsigned short s) {
    return __uint_as_float(((unsigned int)s) << 16);
}

// ---------------- routing: logits -> top2 -> expert lists ----------------
__global__ void routing_kernel(const float* __restrict__ x,
                               const float* __restrict__ gw,
                               int* __restrict__ cnt,
                               int* __restrict__ tok_list,
                               float* __restrict__ tok_w) {
    const int wave = threadIdx.x >> 6;
    const int lane = threadIdx.x & 63;
    const int t = blockIdx.x * 4 + wave;
    if (t >= T_DIM) return;

    float acc[E_NUM];
#pragma unroll
    for (int e = 0; e < E_NUM; ++e) acc[e] = 0.f;
    const float* xr = x + (size_t)t * H_DIM;
    for (int j = lane; j < H_DIM; j += 64) {
        float xv = xr[j];
#pragma unroll
        for (int e = 0; e < E_NUM; ++e)
            acc[e] = fmaf(xv, gw[e * H_DIM + j], acc[e]);
    }
#pragma unroll
    for (int e = 0; e < E_NUM; ++e) {
        float v = acc[e];
#pragma unroll
        for (int off = 32; off > 0; off >>= 1) v += __shfl_xor(v, off);
        acc[e] = v;
    }
    if (lane == 0) {
        int b1 = 0; float l1 = acc[0];
#pragma unroll
        for (int e = 1; e < E_NUM; ++e)
            if (acc[e] > l1) { l1 = acc[e]; b1 = e; }
        int b2 = -1; float l2 = -1e30f;
#pragma unroll
        for (int e = 0; e < E_NUM; ++e)
            if (e != b1 && acc[e] > l2) { l2 = acc[e]; b2 = e; }
        // softmax Z cancels in top-2 renorm: w1 = e^l1/(e^l1+e^l2)
        float w1 = 1.f / (1.f + __expf(l2 - l1));
        float w2 = 1.f - w1;
        int p1 = atomicAdd(&cnt[b1], 1);
        tok_list[b1 * T_DIM + p1] = t; tok_w[b1 * T_DIM + p1] = w1;
        int p2 = atomicAdd(&cnt[b2], 1);
        tok_list[b2 * T_DIM + p2] = t; tok_w[b2 * T_DIM + p2] = w2;
    }
}

// ---------------- scan: padded bases ----------------
__global__ void scan_kernel(const int* __restrict__ cnt, int* __restrict__ base,
                            int* __restrict__ npad, int* __restrict__ total) {
    int acc = 0;
    for (int e = 0; e < E_NUM; ++e) {
        base[e] = acc;
        int p = (cnt[e] + BM - 1) & ~(BM - 1);
        npad[e] = p;
        acc += p;
    }
    *total = acc;
}

// ---------------- GEMM1: gate_up = Xe @ W13^T (gather rows) ----------------
__global__ void __launch_bounds__(256) gemm1_kernel(
    const float* __restrict__ x, const float* __restrict__ ws,
    const int* __restrict__ tok_list,
    const int* __restrict__ cnt, const int* __restrict__ base,
    const int* __restrict__ npad, unsigned short* __restrict__ gu)
{
    const int e = blockIdx.z;
    const int mt = blockIdx.y;
    if (mt * BM >= npad[e]) return;
    const int nt = blockIdx.x;

    __shared__ unsigned short As[BM * BK];
    __shared__ unsigned short Bs[BN * BK];

    const int tid = threadIdx.x;
    const int lane = tid & 63;
    const int wv = tid >> 6;
    const int wm = (wv >> 1) * 64;
    const int wn = (wv & 1) * 64;
    const int quad = lane >> 4;
    const int l16 = lane & 15;

    const int ne = cnt[e];
    const int* tl = tok_list + e * T_DIM + mt * BM;
    const int lim = ne - mt * BM - 1;   // >=0 guaranteed (mt*BM < npad -> < ne)

    const int ar = tid >> 3;            // 0..31
    const int ac = (tid & 7) * 4;       // 0..28

    const float* xb[4];
#pragma unroll
    for (int it = 0; it < 4; ++it) {
        int r = ar + 32 * it;
        int rr = r < lim ? r : lim;
        xb[it] = x + (size_t)tl[rr] * H_DIM + ac;
    }
    const float* w13 = ws + (size_t)e * (2 * I_DIM) * H_DIM
                          + (size_t)(nt * BN) * H_DIM + ac;

    frag_cd acc[4][4];
#pragma unroll
    for (int i = 0; i < 4; ++i)
#pragma unroll
        for (int j = 0; j < 4; ++j)
            acc[i][j] = (frag_cd){0.f, 0.f, 0.f, 0.f};

    for (int k0 = 0; k0 < H_DIM; k0 += BK) {
#pragma unroll
        for (int it = 0; it < 4; ++it) {
            int r = ar + 32 * it;
            float4 v = *(const float4*)(xb[it] + k0);
            *(ushort4*)(&As[r * BK + ac]) =
                make_ushort4(f2bf(v.x), f2bf(v.y), f2bf(v.z), f2bf(v.w));
            float4 w = *(const float4*)(w13 + (size_t)r * H_DIM + k0);
            *(ushort4*)(&Bs[r * BK + ac]) =
                make_ushort4(f2bf(w.x), f2bf(w.y), f2bf(w.z), f2bf(w.w));
        }
        __syncthreads();
        frag_ab af[4], bf[4];
#pragma unroll
        for (int i = 0; i < 4; ++i) {
            af[i] = *(const frag_ab*)(&As[(wm + i * 16 + l16) * BK + quad * 8]);
            bf[i] = *(const frag_ab*)(&Bs[(wn + i * 16 + l16) * BK + quad * 8]);
        }
#pragma unroll
        for (int i = 0; i < 4; ++i)
#pragma unroll
            for (int j = 0; j < 4; ++j)
                acc[i][j] = __builtin_amdgcn_mfma_f32_16x16x32_bf16(
                    af[i], bf[j], acc[i][j], 0, 0, 0);
        __syncthreads();
    }

    const size_t gbase = (size_t)(base[e] + mt * BM);
#pragma unroll
    for (int i = 0; i < 4; ++i) {
#pragma unroll
        for (int r = 0; r < 4; ++r) {
            int row = wm + i * 16 + quad * 4 + r;
            unsigned short* gr = gu + (gbase + row) * (size_t)(2 * I_DIM) + nt * BN + wn;
#pragma unroll
            for (int j = 0; j < 4; ++j)
                gr[j * 16 + l16] = f2bf(acc[i][j][r]);
        }
    }
}

// ---------------- SiLU: h = silu(g)*u, written in-place into gate half ----------------
__global__ void silu_kernel(unsigned short* __restrict__ gu,
                            const int* __restrict__ total) {
    const int tot = *total;
    size_t idx = ((size_t)blockIdx.x * 256 + threadIdx.x) * 4;
    if (idx >= (size_t)tot * I_DIM) return;
    size_t row = idx >> 11;             // / 2048
    int col = (int)(idx & (I_DIM - 1));
    unsigned short* gp = gu + row * (size_t)(2 * I_DIM) + col;
    ushort4 gv = *(const ushort4*)gp;
    ushort4 uv = *(const ushort4*)(gp + I_DIM);
    float g0 = bf2f(gv.x), g1 = bf2f(gv.y), g2 = bf2f(gv.z), g3 = bf2f(gv.w);
    float u0 = bf2f(uv.x), u1 = bf2f(uv.y), u2 = bf2f(uv.z), u3 = bf2f(uv.w);
    float h0 = g0 / (1.f + __expf(-g0)) * u0;
    float h1 = g1 / (1.f + __expf(-g1)) * u1;
    float h2 = g2 / (1.f + __expf(-g2)) * u2;
    float h3 = g3 / (1.f + __expf(-g3)) * u3;
    *(ushort4*)gp = make_ushort4(f2bf(h0), f2bf(h1), f2bf(h2), f2bf(h3));
}

// ---------------- GEMM2: y = H @ W2^T, scatter-add coef*y to out ----------------
__global__ void __launch_bounds__(256) gemm2_kernel(
    const unsigned short* __restrict__ gu, const float* __restrict__ w2s,
    const int* __restrict__ tok_list, const float* __restrict__ tok_w,
    const int* __restrict__ cnt, const int* __restrict__ base,
    const int* __restrict__ npad, float* __restrict__ out)
{
    const int e = blockIdx.z;
    const int mt = blockIdx.y;
    if (mt * BM >= npad[e]) return;
    const int nt = blockIdx.x;

    __shared__ unsigned short As[BM * BK];
    __shared__ unsigned short Bs[BN * BK];
    __shared__ int s_tok[BM];
    __shared__ float s_tw[BM];

    const int tid = threadIdx.x;
    const int lane = tid & 63;
    const int wv = tid >> 6;
    const int wm = (wv >> 1) * 64;
    const int wn = (wv & 1) * 64;
    const int quad = lane >> 4;
    const int l16 = lane & 15;

    const int ne = cnt[e];
    if (tid < BM) {
        int g = mt * BM + tid;
        bool v = g < ne;
        s_tok[tid] = v ? tok_list[e * T_DIM + g] : -1;
        s_tw[tid]  = v ? tok_w[e * T_DIM + g] : 0.f;
    }

    const size_t abase = (size_t)(base[e] + mt * BM);
    const int ar2 = tid >> 2;           // 0..63
    const int ac2 = (tid & 3) * 8;      // 0..24 (ushort units, 16B chunks)
    const unsigned short* ab = gu + (abase + ar2) * (size_t)(2 * I_DIM) + ac2;

    const int ar = tid >> 3;
    const int ac = (tid & 7) * 4;
    const float* w2 = w2s + (size_t)e * H_DIM * I_DIM
                          + (size_t)(nt * BN) * I_DIM + ac;

    frag_cd acc[4][4];
#pragma unroll
    for (int i = 0; i < 4; ++i)
#pragma unroll
        for (int j = 0; j < 4; ++j)
            acc[i][j] = (frag_cd){0.f, 0.f, 0.f, 0.f};

    for (int k0 = 0; k0 < I_DIM; k0 += BK) {
        *(uint4*)(&As[ar2 * BK + ac2]) = *(const uint4*)(ab + k0);
        *(uint4*)(&As[(ar2 + 64) * BK + ac2]) =
            *(const uint4*)(ab + (size_t)64 * (2 * I_DIM) + k0);
#pragma unroll
        for (int it = 0; it < 4; ++it) {
            int r = ar + 32 * it;
            float4 w = *(const float4*)(w2 + (size_t)r * I_DIM + k0);
            *(ushort4*)(&Bs[r * BK + ac]) =
                make_ushort4(f2bf(w.x), f2bf(w.y), f2bf(w.z), f2bf(w.w));
        }
        __syncthreads();
        frag_ab af[4], bf[4];
#pragma unroll
        for (int i = 0; i < 4; ++i) {
            af[i] = *(const frag_ab*)(&As[(wm + i * 16 + l16) * BK + quad * 8]);
            bf[i] = *(const frag_ab*)(&Bs[(wn + i * 16 + l16) * BK + quad * 8]);
        }
#pragma unroll
        for (int i = 0; i < 4; ++i)
#pragma unroll
            for (int j = 0; j < 4; ++j)
                acc[i][j] = __builtin_amdgcn_mfma_f32_16x16x32_bf16(
                    af[i], bf[j], acc[i][j], 0, 0, 0);
        __syncthreads();
    }

#pragma unroll
    for (int i = 0; i < 4; ++i) {
#pragma unroll
        for (int r = 0; r < 4; ++r) {
            int row = wm + i * 16 + quad * 4 + r;
            int tok = s_tok[row];
            if (tok < 0) continue;
            float coef = s_tw[row];
            float* orow = out + (size_t)tok * H_DIM + nt * BN + wn;
#pragma unroll
            for (int j = 0; j < 4; ++j)
                atomicAdd(&orow[j * 16 + l16], coef * acc[i][j][r]);
        }
    }
}

extern "C" void kernel_launch(void* const* d_in, const int* in_sizes, int n_in,
                              void* d_out, int out_size, void* d_ws, size_t ws_size,
                              hipStream_t stream) {
    const float* x   = (const float*)d_in[0];
    const float* gw  = (const float*)d_in[1];
    const float* ws  = (const float*)d_in[2];
    const float* w2s = (const float*)d_in[3];

    char* wsp = (char*)d_ws;
    int*   cnt      = (int*)(wsp + 0);
    int*   basep    = (int*)(wsp + 64);
    int*   npad     = (int*)(wsp + 128);
    int*   total    = (int*)(wsp + 192);
    int*   tok_list = (int*)(wsp + 256);
    float* tok_w    = (float*)(wsp + 256 + 4 * E_NUM * T_DIM);
    unsigned short* gu = (unsigned short*)(wsp + 512 + 8 * E_NUM * T_DIM);
    float* out = (float*)d_out;

    hipMemsetAsync(cnt, 0, 64, stream);
    hipMemsetAsync(d_out, 0, (size_t)T_DIM * H_DIM * sizeof(float), stream);

    routing_kernel<<<T_DIM / 4, 256, 0, stream>>>(x, gw, cnt, tok_list, tok_w);
    scan_kernel<<<1, 1, 0, stream>>>(cnt, basep, npad, total);
    gemm1_kernel<<<dim3(2 * I_DIM / BN, T_DIM / BM, E_NUM), 256, 0, stream>>>(
        x, ws, tok_list, cnt, basep, npad, gu);
    silu_kernel<<<(MAX_ROWS * I_DIM / 4) / 256, 256, 0, stream>>>(gu, total);
    gemm2_kernel<<<dim3(H_DIM / BN, T_DIM / BM, E_NUM), 256, 0, stream>>>(
        gu, w2s, tok_list, tok_w, cnt, basep, npad, out);
}